// Round 1
// baseline (369.895 us; speedup 1.0000x reference)
//
#include <hip/hip_runtime.h>
#include <stdint.h>

typedef __attribute__((ext_vector_type(8))) short bf16x8;   // 8 bf16 in 4 VGPRs
typedef __attribute__((ext_vector_type(4))) float f32x4;

#define M_DIM 8192
#define N_DIM 8192
#define K_DIM 2048

__device__ __forceinline__ unsigned short f2bf(float f) {
  uint32_t b = __builtin_bit_cast(uint32_t, f);
  b = (b + 0x7FFFu + ((b >> 16) & 1u)) >> 16;   // round-to-nearest-even
  return (unsigned short)b;
}

__device__ __forceinline__ unsigned short tern(float w) {
  // sign(hardshrink(w, 0.4)) in bf16 bits: {-1,0,1} exact
  return (fabsf(w) > 0.4f) ? ((w > 0.f) ? (unsigned short)0x3F80 : (unsigned short)0xBF80)
                           : (unsigned short)0;
}

// Fused pre-pass: x (fp32) -> bf16, W (fp32) -> ternary bf16.
__global__ void tl_convert(const float* __restrict__ x, const float* __restrict__ W,
                           unsigned short* __restrict__ xb, unsigned short* __restrict__ wb,
                           int n4) {
  int i = blockIdx.x * blockDim.x + threadIdx.x;
  int stride = gridDim.x * blockDim.x;
  for (; i < n4; i += stride) {
    float4 v = reinterpret_cast<const float4*>(x)[i];
    ushort4 o;
    o.x = f2bf(v.x); o.y = f2bf(v.y); o.z = f2bf(v.z); o.w = f2bf(v.w);
    reinterpret_cast<ushort4*>(xb)[i] = o;
    float4 w = reinterpret_cast<const float4*>(W)[i];
    ushort4 t;
    t.x = tern(w.x); t.y = tern(w.y); t.z = tern(w.z); t.w = tern(w.w);
    reinterpret_cast<ushort4*>(wb)[i] = t;
  }
}

// C[t,o] = sum_k A[t,k] * B[o,k].  A: [M,K] bf16 row-major, B: [N,K] bf16 row-major.
// 128x128 tile, BK=64, 4 waves (2x2), each wave 64x64 via 4x4 frags of 16x16x32 MFMA.
// LDS: linear [128][64] halves; XOR swizzle (row&7)<<3 (half units) applied on the
// global_load_lds SOURCE and on the ds_read address (both-sides rule).
__global__ __launch_bounds__(256, 3)
void tl_gemm(const unsigned short* __restrict__ A, const unsigned short* __restrict__ B,
             float* __restrict__ C) {
  __shared__ unsigned short sA[128 * 64];
  __shared__ unsigned short sB[128 * 64];

  const int tid  = threadIdx.x;
  const int lane = tid & 63;
  const int w    = tid >> 6;       // wave 0..3
  const int wr   = w >> 1;         // wave row (0..1)
  const int wc   = w & 1;          // wave col (0..1)

  // XCD-aware bijective swizzle: nwg = 4096 = 8 * 512
  int bid = blockIdx.x;
  int swz = (bid & 7) * (4096 / 8) + (bid >> 3);
  const int tm = swz >> 6;         // 64 tiles per row of tiles
  const int tn = swz & 63;
  const size_t brow = (size_t)tm * 128;
  const size_t bcol = (size_t)tn * 128;

  // staging geometry: per issue, one wave stages 8 rows x 128B (1024 B)
  const int srow0  = w * 32 + (lane >> 3);   // + j*8
  const int scolh0 = (lane & 7) * 8;         // half-element col base

  f32x4 acc[4][4];
  #pragma unroll
  for (int i = 0; i < 4; ++i)
    #pragma unroll
    for (int j = 0; j < 4; ++j)
      acc[i][j] = f32x4{0.f, 0.f, 0.f, 0.f};

  const int fr = lane & 15;        // fragment row (A: t, B: o)
  const int k8 = lane >> 4;        // k-subgroup 0..3

  for (int kt = 0; kt < K_DIM; kt += 64) {
    // ---- stage A,B tiles (global -> LDS, linear dest, swizzled source) ----
    #pragma unroll
    for (int j = 0; j < 4; ++j) {
      int row  = srow0 + j * 8;
      int colh = scolh0 ^ ((row & 7) << 3);
      const unsigned short* ga = A + (brow + row) * K_DIM + kt + colh;
      const unsigned short* gb = B + (bcol + row) * K_DIM + kt + colh;
      unsigned short* la = &sA[(w * 32 + j * 8) * 64];   // wave-uniform base
      unsigned short* lb = &sB[(w * 32 + j * 8) * 64];
      __builtin_amdgcn_global_load_lds((const __attribute__((address_space(1))) void*)ga,
                                       (__attribute__((address_space(3))) void*)la, 16, 0, 0);
      __builtin_amdgcn_global_load_lds((const __attribute__((address_space(1))) void*)gb,
                                       (__attribute__((address_space(3))) void*)lb, 16, 0, 0);
    }
    __syncthreads();   // drains vmcnt before any wave reads LDS

    // ---- compute: 2 k-halves x 16 MFMA ----
    #pragma unroll
    for (int kk = 0; kk < 2; ++kk) {
      bf16x8 av[4], bv[4];
      #pragma unroll
      for (int mi = 0; mi < 4; ++mi) {
        int row  = wr * 64 + mi * 16 + fr;
        int colh = (kk * 32 + k8 * 8) ^ ((row & 7) << 3);
        av[mi] = *(const bf16x8*)&sA[row * 64 + colh];
      }
      #pragma unroll
      for (int ni = 0; ni < 4; ++ni) {
        int row  = wc * 64 + ni * 16 + fr;
        int colh = (kk * 32 + k8 * 8) ^ ((row & 7) << 3);
        bv[ni] = *(const bf16x8*)&sB[row * 64 + colh];
      }
      #pragma unroll
      for (int mi = 0; mi < 4; ++mi)
        #pragma unroll
        for (int ni = 0; ni < 4; ++ni)
          acc[mi][ni] = __builtin_amdgcn_mfma_f32_16x16x32_bf16(av[mi], bv[ni], acc[mi][ni], 0, 0, 0);
    }
    __syncthreads();
  }

  // ---- epilogue: C/D layout col = lane&15, row = (lane>>4)*4 + reg ----
  #pragma unroll
  for (int mi = 0; mi < 4; ++mi) {
    #pragma unroll
    for (int ni = 0; ni < 4; ++ni) {
      f32x4 v = acc[mi][ni];
      size_t r0 = brow + wr * 64 + mi * 16 + k8 * 4;
      size_t c0 = bcol + wc * 64 + ni * 16 + fr;
      #pragma unroll
      for (int r = 0; r < 4; ++r)
        C[(r0 + r) * N_DIM + c0] = v[r];
    }
  }
}

// Fallback (only if ws_size is unexpectedly small): fused ternarize + fp32 tiled GEMM.
__global__ void tl_naive(const float* __restrict__ x, const float* __restrict__ W,
                         float* __restrict__ out) {
  __shared__ float sx[16][17];
  __shared__ float sw[16][17];
  int tx = threadIdx.x, ty = threadIdx.y;
  int row = blockIdx.y * 16 + ty;   // t
  int col = blockIdx.x * 16 + tx;   // o
  float acc = 0.f;
  for (int kt = 0; kt < K_DIM; kt += 16) {
    sx[ty][tx] = x[(size_t)row * K_DIM + kt + tx];
    float wv = W[(size_t)(blockIdx.x * 16 + ty) * K_DIM + kt + tx];
    sw[ty][tx] = (fabsf(wv) > 0.4f) ? ((wv > 0.f) ? 1.f : -1.f) : 0.f;
    __syncthreads();
    #pragma unroll
    for (int k = 0; k < 16; ++k) acc += sx[ty][k] * sw[tx][k];
    __syncthreads();
  }
  out[(size_t)row * N_DIM + col] = acc;
}

extern "C" void kernel_launch(void* const* d_in, const int* in_sizes, int n_in,
                              void* d_out, int out_size, void* d_ws, size_t ws_size,
                              hipStream_t stream) {
  const float* x = (const float*)d_in[0];
  const float* W = (const float*)d_in[1];
  float* out = (float*)d_out;

  const size_t xb_elems = (size_t)M_DIM * K_DIM;
  const size_t wb_elems = (size_t)N_DIM * K_DIM;
  const size_t need = (xb_elems + wb_elems) * sizeof(unsigned short);   // 64 MiB

  if (ws_size >= need) {
    unsigned short* xb = (unsigned short*)d_ws;
    unsigned short* wb = xb + xb_elems;
    int n4 = (int)(xb_elems / 4);
    tl_convert<<<2048, 256, 0, stream>>>(x, W, xb, wb, n4);
    tl_gemm<<<4096, 256, 0, stream>>>(xb, wb, out);
  } else {
    dim3 g(N_DIM / 16, M_DIM / 16), b(16, 16);
    tl_naive<<<g, b, 0, stream>>>(x, W, out);
  }
}